// Round 1
// baseline (284.845 us; speedup 1.0000x reference)
//
#include <hip/hip_runtime.h>

typedef _Float16 f16;
typedef _Float16 f16x4 __attribute__((ext_vector_type(4)));
typedef _Float16 f16x8 __attribute__((ext_vector_type(8)));
typedef float    f32x4 __attribute__((ext_vector_type(4)));

#define MFMA(a,b,c) __builtin_amdgcn_mfma_f32_16x16x32_f16(a,b,c,0,0,0)

__device__ __forceinline__ void gld16(const void* g, void* l) {
  typedef __attribute__((address_space(1))) unsigned GU;
  typedef __attribute__((address_space(3))) unsigned LU;
  __builtin_amdgcn_global_load_lds((GU*)g, (LU*)l, 16, 0, 0);
}

// ---------------- K0: weight convert / transpose (tiny) ----------------
// Wqt[c][i] = Wq[h][i][k]*0.125 (c=h*64+k, NORM folded exactly: 2^-3)
// Wkt/Wvt same (no scale). Wot[e][hv] = Wo[hv][e].
__global__ __launch_bounds__(256) void conv_w(
    const float* __restrict__ Wq, const float* __restrict__ Wk,
    const float* __restrict__ Wv, const float* __restrict__ Wo,
    f16* __restrict__ Wqt, f16* __restrict__ Wkt, f16* __restrict__ Wvt,
    f16* __restrict__ Wot)
{
  int idx = blockIdx.x * 256 + threadIdx.x;   // 0..262143
  int c = idx & 511, i = idx >> 9;
  int h = c >> 6, k = c & 63;
  int src = (h * 512 + i) * 64 + k;
  Wqt[c * 512 + i] = (f16)(Wq[src] * 0.125f);
  Wkt[c * 512 + i] = (f16)Wk[src];
  Wvt[c * 512 + i] = (f16)Wv[src];
  Wot[idx] = (f16)Wo[(idx & 511) * 512 + (idx >> 9)];
}

// ---------------- K1: fused QKV projection GEMM ----------------
// A = q rows (fp32 -> f16 reg-stage), B = Wt rows via global_load_lds.
// mode0: Qh[m][c] (m=b*512+q), mode1: Kh[m][c] (m=b*3584+g),
// mode2: Vt[((b*8+h)*64+v)][g] (transposed store for attention B-operand).
__global__ __launch_bounds__(256) void proj_kernel(
    const float* __restrict__ q,
    const f16* __restrict__ Wqt, const f16* __restrict__ Wkt, const f16* __restrict__ Wvt,
    f16* __restrict__ Qh, f16* __restrict__ Kh, f16* __restrict__ Vtb)
{
  __shared__ f16 Asl[2][4096];
  __shared__ f16 Bsl[2][4096];

  int bid = blockIdx.x;
  int mode, t;
  if (bid < 128)       { mode = 0; t = bid; }
  else if (bid < 1024) { mode = 1; t = bid - 128; }
  else                 { mode = 2; t = bid - 1024; }
  int rt = t >> 2, ct = t & 3;
  const f16* Wt = (mode == 0) ? Wqt : (mode == 1) ? Wkt : Wvt;

  int tid = threadIdx.x, l = tid & 63, w = tid >> 6;
  int m0 = rt * 128, n0 = ct * 128;
  int wr = w >> 1, wc = w & 1;

  // A staging map: pass p: row p*32+(tid>>3), 4 cols at (tid&7)*4
  int arl = tid >> 3;
  int acol = (tid & 7) * 4;
  int agrow[4], awb[4];
#pragma unroll
  for (int p = 0; p < 4; ++p) {
    int m = m0 + p * 32 + arl;
    int grow;
    if (mode == 0) grow = (m >> 9) * 4096 + (m & 511);
    else { int b = m / 3584; grow = b * 4096 + 512 + (m - b * 3584); }
    agrow[p] = grow * 512;
    int r = p * 32 + arl, cg = tid & 7;
    awb[p] = r * 64 + (((cg >> 1) ^ (r & 3)) << 4) + (cg & 1) * 8;
  }
  // B staging map (global_load_lds, inverse-swizzled source)
  int bn[2], bco[2];
#pragma unroll
  for (int j = 0; j < 2; ++j) {
    int n = (w * 2 + j) * 16 + (l >> 2);
    bn[j] = n;
    bco[j] = ((l & 3) ^ (n & 3)) * 8;
  }

  const f32x4 z4 = {0.f, 0.f, 0.f, 0.f};
  f32x4 acc[4][4];
#pragma unroll
  for (int i = 0; i < 4; ++i)
#pragma unroll
    for (int jj = 0; jj < 4; ++jj) acc[i][jj] = z4;

  f32x4 areg[4];
  auto aload = [&](int k0) {
#pragma unroll
    for (int p = 0; p < 4; ++p)
      areg[p] = *(const f32x4*)(q + agrow[p] + k0 + acol);
  };
  auto bstage = [&](int bufi, int k0) {
#pragma unroll
    for (int j = 0; j < 2; ++j)
      gld16(Wt + (n0 + bn[j]) * 512 + k0 + bco[j], &Bsl[bufi][(w * 2 + j) * 512]);
  };
  auto awrite = [&](int bufi) {
#pragma unroll
    for (int p = 0; p < 4; ++p) {
      f16x4 h4;
      h4[0] = (f16)areg[p][0]; h4[1] = (f16)areg[p][1];
      h4[2] = (f16)areg[p][2]; h4[3] = (f16)areg[p][3];
      *(f16x4*)((char*)&Asl[bufi][0] + awb[p]) = h4;
    }
  };

  aload(0); bstage(0, 0); awrite(0);
  __syncthreads();

  for (int ks = 0; ks < 16; ++ks) {
    int bufi = ks & 1;
    if (ks < 15) { aload((ks + 1) * 32); bstage(bufi ^ 1, (ks + 1) * 32); }
    const char* AB = (const char*)&Asl[bufi][0];
    const char* BB = (const char*)&Bsl[bufi][0];
    f16x8 af[4], bf[4];
#pragma unroll
    for (int mi = 0; mi < 4; ++mi) {
      int row = wr * 64 + mi * 16 + (l & 15);
      af[mi] = *(const f16x8*)(AB + row * 64 + (((l >> 4) ^ (row & 3)) << 4));
    }
#pragma unroll
    for (int ni = 0; ni < 4; ++ni) {
      int rn = wc * 64 + ni * 16 + (l & 15);
      bf[ni] = *(const f16x8*)(BB + rn * 64 + (((l >> 4) ^ (rn & 3)) << 4));
    }
#pragma unroll
    for (int mi = 0; mi < 4; ++mi)
#pragma unroll
      for (int ni = 0; ni < 4; ++ni)
        acc[mi][ni] = MFMA(af[mi], bf[ni], acc[mi][ni]);
    if (ks < 15) awrite(bufi ^ 1);   // T14: fp32 loads landed under the MFMAs
    __syncthreads();
  }

  if (mode < 2) {
    f16* Out = (mode == 0) ? Qh : Kh;
#pragma unroll
    for (int mi = 0; mi < 4; ++mi) {
      int row = m0 + wr * 64 + mi * 16 + (l >> 4) * 4;
#pragma unroll
      for (int ni = 0; ni < 4; ++ni) {
        int col = n0 + wc * 64 + ni * 16 + (l & 15);
#pragma unroll
        for (int r = 0; r < 4; ++r)
          Out[(row + r) * 512 + col] = (f16)acc[mi][ni][r];
      }
    }
  } else {
#pragma unroll
    for (int mi = 0; mi < 4; ++mi) {
      int m = m0 + wr * 64 + mi * 16 + (l >> 4) * 4;
      int b = m / 3584, g = m - b * 3584;   // tiles never cross batch (3584=28*128)
#pragma unroll
      for (int ni = 0; ni < 4; ++ni) {
        int c = n0 + wc * 64 + ni * 16 + (l & 15);
        int hh = c >> 6, v = c & 63;
        f16x4 o4;
        o4[0] = (f16)acc[mi][ni][0]; o4[1] = (f16)acc[mi][ni][1];
        o4[2] = (f16)acc[mi][ni][2]; o4[3] = (f16)acc[mi][ni][3];
        *(f16x4*)(Vtb + ((b * 8 + hh) * 64 + v) * 3584 + g) = o4;
      }
    }
  }
}

// ---------------- K2: flash attention ----------------
// grid: ((b*8)+h)*4+qt, 512 threads = 8 waves, wave = 16 q-rows.
// K/V tiles (64x64 f16) double-buffered via global_load_lds, XOR-swizzled
// both-sides (linear LDS dest + inverse-swizzled global source).
__global__ __launch_bounds__(512) void attn_kernel(
    const f16* __restrict__ Qh, const f16* __restrict__ Kh,
    const f16* __restrict__ Vtb, f16* __restrict__ Hm)
{
  __shared__ f16 Klds[2][4096];
  __shared__ f16 Vlds[2][4096];
  __shared__ f16 Plds[8192];     // 8 waves x [16][64]

  int bid = blockIdx.x;
  int qt = bid & 3, h = (bid >> 2) & 7, bb = bid >> 5;
  int q0 = qt * 128;
  int tid = threadIdx.x, l = tid & 63, w = tid >> 6;

  // Q fragments (NORM already folded into Wqt)
  f16x8 qf0, qf1;
  {
    int qrow = q0 + w * 16 + (l & 15);
    const f16* qb = Qh + (bb * 512 + qrow) * 512 + h * 64 + ((l >> 4) * 8);
    qf0 = *(const f16x8*)qb;
    qf1 = *(const f16x8*)(qb + 32);
  }

  // staging map: waves 0-3 -> K, waves 4-7 -> V (2 wave-instrs each)
  bool isK = (w < 4);
  int sdo[2], ssrc[2];
#pragma unroll
  for (int j = 0; j < 2; ++j) {
    int id = (isK ? w : (w - 4)) * 2 + j;
    int rr = id * 8 + (l >> 3);
    int co = ((l & 7) ^ (rr & 7)) * 8;
    sdo[j] = id * 512;
    if (isK) ssrc[j] = (bb * 3584 + rr) * 512 + h * 64 + co;  // + g0*512
    else     ssrc[j] = ((bb * 8 + h) * 64 + rr) * 3584 + co;  // + g0
  }

  const f32x4 z4 = {0.f, 0.f, 0.f, 0.f};
  f32x4 acco[4];
#pragma unroll
  for (int i = 0; i < 4; ++i) acco[i] = z4;
  float mrow[4], lrow[4];
#pragma unroll
  for (int r = 0; r < 4; ++r) { mrow[r] = -1e30f; lrow[r] = 0.f; }

  char* PwB = (char*)&Plds[w * 1024];

  if (isK) { gld16(Kh + ssrc[0], &Klds[0][sdo[0]]); gld16(Kh + ssrc[1], &Klds[0][sdo[1]]); }
  else     { gld16(Vtb + ssrc[0], &Vlds[0][sdo[0]]); gld16(Vtb + ssrc[1], &Vlds[0][sdo[1]]); }
  __syncthreads();

  int buf = 0;
  for (int it = 0; it < 56; ++it) {
    if (it < 55) {    // prefetch next tile into the other buffer (async)
      int g0 = (it + 1) * 64;
      if (isK) { gld16(Kh + ssrc[0] + g0 * 512, &Klds[buf ^ 1][sdo[0]]);
                 gld16(Kh + ssrc[1] + g0 * 512, &Klds[buf ^ 1][sdo[1]]); }
      else     { gld16(Vtb + ssrc[0] + g0, &Vlds[buf ^ 1][sdo[0]]);
                 gld16(Vtb + ssrc[1] + g0, &Vlds[buf ^ 1][sdo[1]]); }
    }
    const char* KB = (const char*)&Klds[buf][0];
    const char* VB = (const char*)&Vlds[buf][0];

    // S = Q K^T (per wave: 16 q-rows x 64 g)
    f32x4 accs[4];
#pragma unroll
    for (int i = 0; i < 4; ++i) accs[i] = z4;
#pragma unroll
    for (int ni = 0; ni < 4; ++ni) {
      int g = ni * 16 + (l & 15);
      f16x8 kb0 = *(const f16x8*)(KB + g * 128 + ((((l >> 4)    ) ^ (g & 7)) << 4));
      f16x8 kb1 = *(const f16x8*)(KB + g * 128 + (((4 + (l >> 4)) ^ (g & 7)) << 4));
      accs[ni] = MFMA(qf0, kb0, accs[ni]);
      accs[ni] = MFMA(qf1, kb1, accs[ni]);
    }

    // online softmax (lane owns rows (l>>4)*4+r; reduce over g via 16-lane shfl)
    float alpha[4];
#pragma unroll
    for (int r = 0; r < 4; ++r) {
      float tm = fmaxf(fmaxf(accs[0][r], accs[1][r]), fmaxf(accs[2][r], accs[3][r]));
      tm = fmaxf(tm, __shfl_xor(tm, 1));
      tm = fmaxf(tm, __shfl_xor(tm, 2));
      tm = fmaxf(tm, __shfl_xor(tm, 4));
      tm = fmaxf(tm, __shfl_xor(tm, 8));
      float mn = fmaxf(mrow[r], tm);
      alpha[r] = __expf(mrow[r] - mn);
      mrow[r] = mn;
    }
    float rsum[4] = {0.f, 0.f, 0.f, 0.f};
    int qbase = (l >> 4) * 4;
#pragma unroll
    for (int ni = 0; ni < 4; ++ni) {
      int g = ni * 16 + (l & 15);
#pragma unroll
      for (int r = 0; r < 4; ++r) {
        float p = __expf(accs[ni][r] - mrow[r]);
        rsum[r] += p;
        int qq = qbase + r;
        *(f16*)(PwB + qq * 128 + ((((g >> 3) ^ (qq & 7))) << 4) + (g & 7) * 2) = (f16)p;
      }
    }
#pragma unroll
    for (int r = 0; r < 4; ++r) {
      rsum[r] += __shfl_xor(rsum[r], 1);
      rsum[r] += __shfl_xor(rsum[r], 2);
      rsum[r] += __shfl_xor(rsum[r], 4);
      rsum[r] += __shfl_xor(rsum[r], 8);
      lrow[r] = lrow[r] * alpha[r] + rsum[r];
    }
#pragma unroll
    for (int ni = 0; ni < 4; ++ni)
#pragma unroll
      for (int r = 0; r < 4; ++r) acco[ni][r] *= alpha[r];

    asm volatile("s_waitcnt lgkmcnt(0)" ::: "memory");   // P writes visible (wave-local)

    // O += P V
#pragma unroll
    for (int kc = 0; kc < 2; ++kc) {
      int qq = l & 15;
      int ch = kc * 4 + (l >> 4);
      f16x8 pa = *(const f16x8*)(PwB + qq * 128 + ((ch ^ (qq & 7)) << 4));
#pragma unroll
      for (int ni = 0; ni < 4; ++ni) {
        int v = ni * 16 + (l & 15);
        f16x8 vb = *(const f16x8*)(VB + v * 128 + ((ch ^ (v & 7)) << 4));
        acco[ni] = MFMA(pa, vb, acco[ni]);
      }
    }

    __syncthreads();   // readers done with buf; prefetched buf^1 landed
    buf ^= 1;
  }

#pragma unroll
  for (int r = 0; r < 4; ++r) {
    float inv = 1.f / lrow[r];
    int qrow = q0 + w * 16 + (l >> 4) * 4 + r;
    f16* ob = Hm + (bb * 512 + qrow) * 512 + h * 64 + (l & 15);
#pragma unroll
    for (int ni = 0; ni < 4; ++ni)
      ob[ni * 16] = (f16)(acco[ni][r] * inv);
  }
}

// ---------------- K3: output projection GEMM ----------------
__global__ __launch_bounds__(256) void outproj_kernel(
    const f16* __restrict__ Hm, const f16* __restrict__ Wot, float* __restrict__ out)
{
  __shared__ f16 Asl[2][4096];
  __shared__ f16 Bsl[2][4096];
  int bid = blockIdx.x;
  int rt = bid >> 2, ct = bid & 3;
  int tid = threadIdx.x, l = tid & 63, w = tid >> 6;
  int m0 = rt * 128, n0 = ct * 128;
  int wr = w >> 1, wc = w & 1;

  int an[2], aco[2];
#pragma unroll
  for (int j = 0; j < 2; ++j) {
    int r = (w * 2 + j) * 16 + (l >> 2);
    an[j] = r;
    aco[j] = ((l & 3) ^ (r & 3)) * 8;
  }

  const f32x4 z4 = {0.f, 0.f, 0.f, 0.f};
  f32x4 acc[4][4];
#pragma unroll
  for (int i = 0; i < 4; ++i)
#pragma unroll
    for (int jj = 0; jj < 4; ++jj) acc[i][jj] = z4;

  auto stage = [&](int bufi, int k0) {
#pragma unroll
    for (int j = 0; j < 2; ++j) {
      gld16(Hm  + (m0 + an[j]) * 512 + k0 + aco[j], &Asl[bufi][(w * 2 + j) * 512]);
      gld16(Wot + (n0 + an[j]) * 512 + k0 + aco[j], &Bsl[bufi][(w * 2 + j) * 512]);
    }
  };

  stage(0, 0);
  __syncthreads();
  for (int ks = 0; ks < 16; ++ks) {
    int bufi = ks & 1;
    if (ks < 15) stage(bufi ^ 1, (ks + 1) * 32);
    const char* AB = (const char*)&Asl[bufi][0];
    const char* BB = (const char*)&Bsl[bufi][0];
    f16x8 af[4], bf[4];
#pragma unroll
    for (int mi = 0; mi < 4; ++mi) {
      int row = wr * 64 + mi * 16 + (l & 15);
      af[mi] = *(const f16x8*)(AB + row * 64 + (((l >> 4) ^ (row & 3)) << 4));
    }
#pragma unroll
    for (int ni = 0; ni < 4; ++ni) {
      int rn = wc * 64 + ni * 16 + (l & 15);
      bf[ni] = *(const f16x8*)(BB + rn * 64 + (((l >> 4) ^ (rn & 3)) << 4));
    }
#pragma unroll
    for (int mi = 0; mi < 4; ++mi)
#pragma unroll
      for (int ni = 0; ni < 4; ++ni)
        acc[mi][ni] = MFMA(af[mi], bf[ni], acc[mi][ni]);
    __syncthreads();
  }

#pragma unroll
  for (int mi = 0; mi < 4; ++mi) {
    int row = m0 + wr * 64 + mi * 16 + (l >> 4) * 4;
#pragma unroll
    for (int ni = 0; ni < 4; ++ni) {
      int col = n0 + wc * 64 + ni * 16 + (l & 15);
#pragma unroll
      for (int r = 0; r < 4; ++r)
        out[(row + r) * 512 + col] = acc[mi][ni][r];
    }
  }
}

extern "C" void kernel_launch(void* const* d_in, const int* in_sizes, int n_in,
                              void* d_out, int out_size, void* d_ws, size_t ws_size,
                              hipStream_t stream) {
  const float* q  = (const float*)d_in[0];
  const float* Wq = (const float*)d_in[1];
  const float* Wk = (const float*)d_in[2];
  const float* Wv = (const float*)d_in[3];
  const float* Wo = (const float*)d_in[4];
  float* out = (float*)d_out;

  f16* ws  = (f16*)d_ws;               // total ~66 MB of workspace used
  f16* Wqt = ws;                       // 512*512
  f16* Wkt = Wqt + 262144;
  f16* Wvt = Wkt + 262144;
  f16* Wot = Wvt + 262144;
  f16* Qh  = Wot + 262144;             // 4096*512
  f16* Kh  = Qh  + 4096 * 512;         // 28672*512
  f16* Vtb = Kh  + 28672 * 512;        // 64*8*8 rows x 3584
  f16* Hm  = Vtb + 28672 * 512;        // 4096*512

  conv_w<<<dim3(1024), dim3(256), 0, stream>>>(Wq, Wk, Wv, Wo, Wqt, Wkt, Wvt, Wot);
  proj_kernel<<<dim3(1920), dim3(256), 0, stream>>>(q, Wqt, Wkt, Wvt, Qh, Kh, Vtb);
  attn_kernel<<<dim3(256), dim3(512), 0, stream>>>(Qh, Kh, Vtb, Hm);
  outproj_kernel<<<dim3(128), dim3(256), 0, stream>>>(Hm, Wot, out);
}

// Round 2
// 243.084 us; speedup vs baseline: 1.1718x; 1.1718x over previous
//
#include <hip/hip_runtime.h>

typedef _Float16 f16;
typedef _Float16 f16x4 __attribute__((ext_vector_type(4)));
typedef _Float16 f16x8 __attribute__((ext_vector_type(8)));
typedef float    f32x4 __attribute__((ext_vector_type(4)));

#define MFMA(a,b,c) __builtin_amdgcn_mfma_f32_16x16x32_f16(a,b,c,0,0,0)

#if __has_builtin(__builtin_amdgcn_exp2f)
#define EXP2(x) __builtin_amdgcn_exp2f(x)
#else
#define EXP2(x) exp2f(x)
#endif

__device__ __forceinline__ void gld16(const void* g, void* l) {
  typedef __attribute__((address_space(1))) unsigned GU;
  typedef __attribute__((address_space(3))) unsigned LU;
  __builtin_amdgcn_global_load_lds((GU*)g, (LU*)l, 16, 0, 0);
}

// ---------------- K0: weight transpose via LDS tiles (coalesced both sides) ----
// mats 0-2: Wt[c][i] = W[h][i][k], c=h*64+k; mat0 scaled by 0.125*log2(e)
// (softmax moved to exp2 domain; 1/8 NORM folded exactly).
// mat 3: Wot[e][hv] = Wo[hv][e].
__global__ __launch_bounds__(256) void transp_w(
    const float* __restrict__ Wq, const float* __restrict__ Wk,
    const float* __restrict__ Wv, const float* __restrict__ Wo,
    f16* __restrict__ Wqt, f16* __restrict__ Wkt, f16* __restrict__ Wvt,
    f16* __restrict__ Wot)
{
  __shared__ float T[64 * 65];
  int bid = blockIdx.x, t = threadIdx.x;
  int mat = bid >> 6;
  int i0 = (bid & 7) * 64, c0 = ((bid >> 3) & 7) * 64;
  const float* src; f16* dst; float scale = 1.f;
  if      (mat == 0) { src = Wq; dst = Wqt; scale = 0.125f * 1.4426950408889634f; }
  else if (mat == 1) { src = Wk; dst = Wkt; }
  else if (mat == 2) { src = Wv; dst = Wvt; }
  else               { src = Wo; dst = Wot; }
#pragma unroll
  for (int p = 0; p < 4; ++p) {
    int row = p * 16 + (t >> 4), col = (t & 15) * 4;
    const float* a = (mat < 3)
        ? src + ((c0 >> 6) * 512 + i0 + row) * 64 + col
        : src + (i0 + row) * 512 + c0 + col;
    f32x4 v = *(const f32x4*)a;
    T[row * 65 + col + 0] = v[0] * scale;
    T[row * 65 + col + 1] = v[1] * scale;
    T[row * 65 + col + 2] = v[2] * scale;
    T[row * 65 + col + 3] = v[3] * scale;
  }
  __syncthreads();
#pragma unroll
  for (int p = 0; p < 16; ++p) {
    int cc = (t >> 6) * 16 + p, ii = t & 63;
    dst[(c0 + cc) * 512 + i0 + ii] = (f16)T[ii * 65 + cc];
  }
}

// ---------------- K1: fused QKV projection GEMM (unchanged from R1) ----------
__global__ __launch_bounds__(256) void proj_kernel(
    const float* __restrict__ q,
    const f16* __restrict__ Wqt, const f16* __restrict__ Wkt, const f16* __restrict__ Wvt,
    f16* __restrict__ Qh, f16* __restrict__ Kh, f16* __restrict__ Vtb)
{
  __shared__ f16 Asl[2][4096];
  __shared__ f16 Bsl[2][4096];

  int bid = blockIdx.x;
  int mode, t;
  if (bid < 128)       { mode = 0; t = bid; }
  else if (bid < 1024) { mode = 1; t = bid - 128; }
  else                 { mode = 2; t = bid - 1024; }
  int rt = t >> 2, ct = t & 3;
  const f16* Wt = (mode == 0) ? Wqt : (mode == 1) ? Wkt : Wvt;

  int tid = threadIdx.x, l = tid & 63, w = tid >> 6;
  int m0 = rt * 128, n0 = ct * 128;
  int wr = w >> 1, wc = w & 1;

  int arl = tid >> 3;
  int acol = (tid & 7) * 4;
  int agrow[4], awb[4];
#pragma unroll
  for (int p = 0; p < 4; ++p) {
    int m = m0 + p * 32 + arl;
    int grow;
    if (mode == 0) grow = (m >> 9) * 4096 + (m & 511);
    else { int b = m / 3584; grow = b * 4096 + 512 + (m - b * 3584); }
    agrow[p] = grow * 512;
    int r = p * 32 + arl, cg = tid & 7;
    awb[p] = r * 64 + (((cg >> 1) ^ (r & 3)) << 4) + (cg & 1) * 8;
  }
  int bn[2], bco[2];
#pragma unroll
  for (int j = 0; j < 2; ++j) {
    int n = (w * 2 + j) * 16 + (l >> 2);
    bn[j] = n;
    bco[j] = ((l & 3) ^ (n & 3)) * 8;
  }

  const f32x4 z4 = {0.f, 0.f, 0.f, 0.f};
  f32x4 acc[4][4];
#pragma unroll
  for (int i = 0; i < 4; ++i)
#pragma unroll
    for (int jj = 0; jj < 4; ++jj) acc[i][jj] = z4;

  f32x4 areg[4];
  auto aload = [&](int k0) {
#pragma unroll
    for (int p = 0; p < 4; ++p)
      areg[p] = *(const f32x4*)(q + agrow[p] + k0 + acol);
  };
  auto bstage = [&](int bufi, int k0) {
#pragma unroll
    for (int j = 0; j < 2; ++j)
      gld16(Wt + (n0 + bn[j]) * 512 + k0 + bco[j], &Bsl[bufi][(w * 2 + j) * 512]);
  };
  auto awrite = [&](int bufi) {
#pragma unroll
    for (int p = 0; p < 4; ++p) {
      f16x4 h4;
      h4[0] = (f16)areg[p][0]; h4[1] = (f16)areg[p][1];
      h4[2] = (f16)areg[p][2]; h4[3] = (f16)areg[p][3];
      *(f16x4*)((char*)&Asl[bufi][0] + awb[p]) = h4;
    }
  };

  aload(0); bstage(0, 0); awrite(0);
  __syncthreads();

  for (int ks = 0; ks < 16; ++ks) {
    int bufi = ks & 1;
    if (ks < 15) { aload((ks + 1) * 32); bstage(bufi ^ 1, (ks + 1) * 32); }
    const char* AB = (const char*)&Asl[bufi][0];
    const char* BB = (const char*)&Bsl[bufi][0];
    f16x8 af[4], bf[4];
#pragma unroll
    for (int mi = 0; mi < 4; ++mi) {
      int row = wr * 64 + mi * 16 + (l & 15);
      af[mi] = *(const f16x8*)(AB + row * 64 + (((l >> 4) ^ (row & 3)) << 4));
    }
#pragma unroll
    for (int ni = 0; ni < 4; ++ni) {
      int rn = wc * 64 + ni * 16 + (l & 15);
      bf[ni] = *(const f16x8*)(BB + rn * 64 + (((l >> 4) ^ (rn & 3)) << 4));
    }
#pragma unroll
    for (int mi = 0; mi < 4; ++mi)
#pragma unroll
      for (int ni = 0; ni < 4; ++ni)
        acc[mi][ni] = MFMA(af[mi], bf[ni], acc[mi][ni]);
    if (ks < 15) awrite(bufi ^ 1);
    __syncthreads();
  }

  if (mode < 2) {
    f16* Out = (mode == 0) ? Qh : Kh;
#pragma unroll
    for (int mi = 0; mi < 4; ++mi) {
      int row = m0 + wr * 64 + mi * 16 + (l >> 4) * 4;
#pragma unroll
      for (int ni = 0; ni < 4; ++ni) {
        int col = n0 + wc * 64 + ni * 16 + (l & 15);
#pragma unroll
        for (int r = 0; r < 4; ++r)
          Out[(row + r) * 512 + col] = (f16)acc[mi][ni][r];
      }
    }
  } else {
#pragma unroll
    for (int mi = 0; mi < 4; ++mi) {
      int m = m0 + wr * 64 + mi * 16 + (l >> 4) * 4;
      int b = m / 3584, g = m - b * 3584;
#pragma unroll
      for (int ni = 0; ni < 4; ++ni) {
        int c = n0 + wc * 64 + ni * 16 + (l & 15);
        int hh = c >> 6, v = c & 63;
        f16x4 o4;
        o4[0] = (f16)acc[mi][ni][0]; o4[1] = (f16)acc[mi][ni][1];
        o4[2] = (f16)acc[mi][ni][2]; o4[3] = (f16)acc[mi][ni][3];
        *(f16x4*)(Vtb + ((b * 8 + hh) * 64 + v) * 3584 + g) = o4;
      }
    }
  }
}

// ---------------- K2: flash attention, split-KV x2, swapped-QK^T -------------
// grid 512: seg=bid&1, qt=(bid>>1)&3, h=(bid>>3)&7, bb=bid>>6. 8 waves x 16 q.
// S^T = mfma(Kfrag, Qfrag): lane owns full q-row (q=l&15) -> in-lane softmax,
// 2 shfl_xor only. P^T staged per-wave in padded LDS (stride 72 f16).
// O^T = mfma(V^Tfrag, P^Tfrag). exp2 domain (log2e folded into Wqt).
__global__ __launch_bounds__(512, 4) void attn_kernel(
    const f16* __restrict__ Qh, const f16* __restrict__ Kh,
    const f16* __restrict__ Vtb, f16* __restrict__ Opart,
    float* __restrict__ Ml, float* __restrict__ Ll)
{
  __shared__ f16 Klds[2][4096];
  __shared__ f16 Vlds[2][4096];
  __shared__ f16 Plds[8 * 1152];   // 8 waves x 16 rows x 72 f16 (pad: no conflicts)

  int bid = blockIdx.x;
  int seg = bid & 1, qt = (bid >> 1) & 3, h = (bid >> 3) & 7, bb = bid >> 6;
  int q0 = qt * 128;
  int tid = threadIdx.x, l = tid & 63, w = tid >> 6;

  // Q fragment: lane holds Q[q=l&15 row][k=(l>>4)*8+j] — serves as B-operand.
  f16x8 qf0, qf1;
  {
    int qrow = q0 + w * 16 + (l & 15);
    const f16* qb = Qh + (bb * 512 + qrow) * 512 + h * 64 + ((l >> 4) * 8);
    qf0 = *(const f16x8*)qb;
    qf1 = *(const f16x8*)(qb + 32);
  }

  bool isK = (w < 4);
  int sdo[2], ssrc[2];
#pragma unroll
  for (int j = 0; j < 2; ++j) {
    int id = (isK ? w : (w - 4)) * 2 + j;
    int rr = id * 8 + (l >> 3);
    int co = ((l & 7) ^ (rr & 7)) * 8;
    sdo[j] = id * 512;
    if (isK) ssrc[j] = (bb * 3584 + seg * 1792 + rr) * 512 + h * 64 + co;
    else     ssrc[j] = ((bb * 8 + h) * 64 + rr) * 3584 + seg * 1792 + co;
  }

  const f32x4 z4 = {0.f, 0.f, 0.f, 0.f};
  f32x4 acco[4];
#pragma unroll
  for (int i = 0; i < 4; ++i) acco[i] = z4;
  float mrow = -1e30f, lrow = 0.f;

  char* PwB = (char*)&Plds[w * 1152];
  int pwbase = (l & 15) * 144 + (l >> 4) * 8;   // write base (b64)
  int prbase = (l & 15) * 144 + (l >> 4) * 16;  // read base (b128)

  if (isK) { gld16(Kh + ssrc[0], &Klds[0][sdo[0]]); gld16(Kh + ssrc[1], &Klds[0][sdo[1]]); }
  else     { gld16(Vtb + ssrc[0], &Vlds[0][sdo[0]]); gld16(Vtb + ssrc[1], &Vlds[0][sdo[1]]); }
  __syncthreads();

  int buf = 0;
  for (int it = 0; it < 28; ++it) {
    if (it < 27) {
      int g0 = (it + 1) * 64;
      if (isK) { gld16(Kh + ssrc[0] + g0 * 512, &Klds[buf ^ 1][sdo[0]]);
                 gld16(Kh + ssrc[1] + g0 * 512, &Klds[buf ^ 1][sdo[1]]); }
      else     { gld16(Vtb + ssrc[0] + g0, &Vlds[buf ^ 1][sdo[0]]);
                 gld16(Vtb + ssrc[1] + g0, &Vlds[buf ^ 1][sdo[1]]); }
    }
    const char* KB = (const char*)&Klds[buf][0];
    const char* VB = (const char*)&Vlds[buf][0];

    // S^T: accs[ni] C-layout col=q(l&15), row=g_local=(l>>4)*4+r
    f32x4 accs[4];
#pragma unroll
    for (int i = 0; i < 4; ++i) accs[i] = z4;
#pragma unroll
    for (int ni = 0; ni < 4; ++ni) {
      int g = ni * 16 + (l & 15);
      const char* rp = KB + g * 128;
      f16x8 k0 = *(const f16x8*)(rp + ((((l >> 4)    ) ^ (g & 7)) << 4));
      f16x8 k1 = *(const f16x8*)(rp + (((4 + (l >> 4)) ^ (g & 7)) << 4));
      accs[ni] = MFMA(k0, qf0, accs[ni]);
      accs[ni] = MFMA(k1, qf1, accs[ni]);
    }

    // in-lane softmax for q-row (lane holds 16 of 64 g; rest via 2 shfl)
    float n0 = fmaxf(fmaxf(accs[0][0], accs[0][1]), fmaxf(accs[0][2], accs[0][3]));
    float n1 = fmaxf(fmaxf(accs[1][0], accs[1][1]), fmaxf(accs[1][2], accs[1][3]));
    float n2 = fmaxf(fmaxf(accs[2][0], accs[2][1]), fmaxf(accs[2][2], accs[2][3]));
    float n3 = fmaxf(fmaxf(accs[3][0], accs[3][1]), fmaxf(accs[3][2], accs[3][3]));
    float tm = fmaxf(fmaxf(n0, n1), fmaxf(n2, n3));
    tm = fmaxf(tm, __shfl_xor(tm, 16));
    tm = fmaxf(tm, __shfl_xor(tm, 32));
    float mn = fmaxf(mrow, tm);
    float alpha = EXP2(mrow - mn);
    mrow = mn;

    float rs = 0.f;
#pragma unroll
    for (int ni = 0; ni < 4; ++ni) {
      float s0 = EXP2(accs[ni][0] - mrow);
      float s1 = EXP2(accs[ni][1] - mrow);
      float s2 = EXP2(accs[ni][2] - mrow);
      float s3 = EXP2(accs[ni][3] - mrow);
      rs += (s0 + s1) + (s2 + s3);
      f16x4 p4;
      p4[0] = (f16)s0; p4[1] = (f16)s1; p4[2] = (f16)s2; p4[3] = (f16)s3;
      *(f16x4*)(PwB + pwbase + ni * 32) = p4;
    }
    rs += __shfl_xor(rs, 16);
    rs += __shfl_xor(rs, 32);
    lrow = lrow * alpha + rs;
#pragma unroll
    for (int ni = 0; ni < 4; ++ni)
#pragma unroll
      for (int r = 0; r < 4; ++r) acco[ni][r] *= alpha;

    asm volatile("s_waitcnt lgkmcnt(0)" ::: "memory");  // P writes visible (wave-local)

    // O^T += V^T P^T : A = V^T rows v, B = P^T (lane: P[q=l&15][g chunk])
#pragma unroll
    for (int kc = 0; kc < 2; ++kc) {
      f16x8 pf = *(const f16x8*)(PwB + prbase + kc * 64);
#pragma unroll
      for (int ni = 0; ni < 4; ++ni) {
        int v = ni * 16 + (l & 15);
        f16x8 vf = *(const f16x8*)(VB + v * 128 + (((kc * 4 + (l >> 4)) ^ (v & 7)) << 4));
        acco[ni] = MFMA(vf, pf, acco[ni]);
      }
    }

    __syncthreads();
    buf ^= 1;
  }

  // epilogue: per-segment normalized O^T (f16) + m,l (f32)
  float inv = 1.f / lrow;
  int q = q0 + w * 16 + (l & 15);
  size_t obase = ((size_t)(seg * 64 + bb * 8 + h) * 512 + q) * 64;
#pragma unroll
  for (int ni = 0; ni < 4; ++ni) {
    f16x4 o4;
    o4[0] = (f16)(acco[ni][0] * inv); o4[1] = (f16)(acco[ni][1] * inv);
    o4[2] = (f16)(acco[ni][2] * inv); o4[3] = (f16)(acco[ni][3] * inv);
    *(f16x4*)(Opart + obase + ni * 16 + (l >> 4) * 4) = o4;
  }
  if ((l >> 4) == 0) {
    int mi = (seg * 64 + bb * 8 + h) * 512 + q;
    Ml[mi] = mrow; Ll[mi] = lrow;
  }
}

// ---------------- K2b: merge the two KV segments ----------------
__global__ __launch_bounds__(256) void merge_kernel(
    const f16* __restrict__ Opart, const float* __restrict__ Ml,
    const float* __restrict__ Ll, f16* __restrict__ Hm)
{
  int row = blockIdx.x * 4 + (threadIdx.x >> 6);
  int l = threadIdx.x & 63;
  int bh = row >> 9, q = row & 511;
  int i0 = bh * 512 + q;
  int i1 = (64 + bh) * 512 + q;
  float o0 = (float)Opart[(size_t)i0 * 64 + l];
  float o1 = (float)Opart[(size_t)i1 * 64 + l];
  float m0 = Ml[i0], l0 = Ll[i0], m1 = Ml[i1], l1 = Ll[i1];
  float m = fmaxf(m0, m1);
  float w0 = EXP2(m0 - m) * l0, w1 = EXP2(m1 - m) * l1;
  float o = (w0 * o0 + w1 * o1) / (w0 + w1);
  int bb = bh >> 3, hh = bh & 7;
  Hm[((size_t)(bb * 512 + q)) * 512 + hh * 64 + l] = (f16)o;
}

// ---------------- K3: output projection GEMM (unchanged from R1) -------------
__global__ __launch_bounds__(256) void outproj_kernel(
    const f16* __restrict__ Hm, const f16* __restrict__ Wot, float* __restrict__ out)
{
  __shared__ f16 Asl[2][4096];
  __shared__ f16 Bsl[2][4096];
  int bid = blockIdx.x;
  int rt = bid >> 2, ct = bid & 3;
  int tid = threadIdx.x, l = tid & 63, w = tid >> 6;
  int m0 = rt * 128, n0 = ct * 128;
  int wr = w >> 1, wc = w & 1;

  int an[2], aco[2];
#pragma unroll
  for (int j = 0; j < 2; ++j) {
    int r = (w * 2 + j) * 16 + (l >> 2);
    an[j] = r;
    aco[j] = ((l & 3) ^ (r & 3)) * 8;
  }

  const f32x4 z4 = {0.f, 0.f, 0.f, 0.f};
  f32x4 acc[4][4];
#pragma unroll
  for (int i = 0; i < 4; ++i)
#pragma unroll
    for (int jj = 0; jj < 4; ++jj) acc[i][jj] = z4;

  auto stage = [&](int bufi, int k0) {
#pragma unroll
    for (int j = 0; j < 2; ++j) {
      gld16(Hm  + (m0 + an[j]) * 512 + k0 + aco[j], &Asl[bufi][(w * 2 + j) * 512]);
      gld16(Wot + (n0 + an[j]) * 512 + k0 + aco[j], &Bsl[bufi][(w * 2 + j) * 512]);
    }
  };

  stage(0, 0);
  __syncthreads();
  for (int ks = 0; ks < 16; ++ks) {
    int bufi = ks & 1;
    if (ks < 15) stage(bufi ^ 1, (ks + 1) * 32);
    const char* AB = (const char*)&Asl[bufi][0];
    const char* BB = (const char*)&Bsl[bufi][0];
    f16x8 af[4], bf[4];
#pragma unroll
    for (int mi = 0; mi < 4; ++mi) {
      int row = wr * 64 + mi * 16 + (l & 15);
      af[mi] = *(const f16x8*)(AB + row * 64 + (((l >> 4) ^ (row & 3)) << 4));
    }
#pragma unroll
    for (int ni = 0; ni < 4; ++ni) {
      int rn = wc * 64 + ni * 16 + (l & 15);
      bf[ni] = *(const f16x8*)(BB + rn * 64 + (((l >> 4) ^ (rn & 3)) << 4));
    }
#pragma unroll
    for (int mi = 0; mi < 4; ++mi)
#pragma unroll
      for (int ni = 0; ni < 4; ++ni)
        acc[mi][ni] = MFMA(af[mi], bf[ni], acc[mi][ni]);
    __syncthreads();
  }

#pragma unroll
  for (int mi = 0; mi < 4; ++mi) {
    int row = m0 + wr * 64 + mi * 16 + (l >> 4) * 4;
#pragma unroll
    for (int ni = 0; ni < 4; ++ni) {
      int col = n0 + wc * 64 + ni * 16 + (l & 15);
#pragma unroll
      for (int r = 0; r < 4; ++r)
        out[(row + r) * 512 + col] = acc[mi][ni][r];
    }
  }
}

extern "C" void kernel_launch(void* const* d_in, const int* in_sizes, int n_in,
                              void* d_out, int out_size, void* d_ws, size_t ws_size,
                              hipStream_t stream) {
  const float* q  = (const float*)d_in[0];
  const float* Wq = (const float*)d_in[1];
  const float* Wk = (const float*)d_in[2];
  const float* Wv = (const float*)d_in[3];
  const float* Wo = (const float*)d_in[4];
  float* out = (float*)d_out;

  f16* ws  = (f16*)d_ws;
  f16* Wqt = ws;                        // 262144
  f16* Wkt = Wqt + 262144;
  f16* Wvt = Wkt + 262144;
  f16* Wot = Wvt + 262144;
  f16* Qh  = Wot + 262144;              // 4096*512
  f16* Kh  = Qh  + 4096 * 512;          // 28672*512
  f16* Vtb = Kh  + 28672 * 512;         // 28672*512 (transposed V)
  f16* Opart = Vtb + 28672 * 512;       // 2*64*512*64 (segment-normalized O^T)
  float* Ml = (float*)(Opart + 2 * 64 * 512 * 64);  // 2*64*512
  float* Ll = Ml + 65536;
  f16* Hm = Qh;                         // reuse: attn done before merge writes

  transp_w<<<dim3(256),  dim3(256), 0, stream>>>(Wq, Wk, Wv, Wo, Wqt, Wkt, Wvt, Wot);
  proj_kernel<<<dim3(1920), dim3(256), 0, stream>>>(q, Wqt, Wkt, Wvt, Qh, Kh, Vtb);
  attn_kernel<<<dim3(512), dim3(512), 0, stream>>>(Qh, Kh, Vtb, Opart, Ml, Ll);
  merge_kernel<<<dim3(8192), dim3(256), 0, stream>>>(Opart, Ml, Ll, Hm);
  outproj_kernel<<<dim3(128), dim3(256), 0, stream>>>(Hm, Wot, out);
}

// Round 3
// 242.544 us; speedup vs baseline: 1.1744x; 1.0022x over previous
//
#include <hip/hip_runtime.h>

typedef _Float16 f16;
typedef _Float16 f16x4 __attribute__((ext_vector_type(4)));
typedef _Float16 f16x8 __attribute__((ext_vector_type(8)));
typedef float    f32x4 __attribute__((ext_vector_type(4)));

#define MFMA(a,b,c) __builtin_amdgcn_mfma_f32_16x16x32_f16(a,b,c,0,0,0)

#if __has_builtin(__builtin_amdgcn_exp2f)
#define EXP2(x) __builtin_amdgcn_exp2f(x)
#else
#define EXP2(x) exp2f(x)
#endif

__device__ __forceinline__ void gld16(const void* g, void* l) {
  typedef __attribute__((address_space(1))) unsigned GU;
  typedef __attribute__((address_space(3))) unsigned LU;
  __builtin_amdgcn_global_load_lds((GU*)g, (LU*)l, 16, 0, 0);
}

// ---------------- K0: weight transpose via LDS tiles ----------------
// mats 0-2: Wt[c][i] = W[h][i][k], c=h*64+k; mat0 scaled by 0.125*log2(e).
// mat 3: Wot[e][hv] = Wo[hv][e].
__global__ __launch_bounds__(256) void transp_w(
    const float* __restrict__ Wq, const float* __restrict__ Wk,
    const float* __restrict__ Wv, const float* __restrict__ Wo,
    f16* __restrict__ Wqt, f16* __restrict__ Wkt, f16* __restrict__ Wvt,
    f16* __restrict__ Wot)
{
  __shared__ float T[64 * 65];
  int bid = blockIdx.x, t = threadIdx.x;
  int mat = bid >> 6;
  int i0 = (bid & 7) * 64, c0 = ((bid >> 3) & 7) * 64;
  const float* src; f16* dst; float scale = 1.f;
  if      (mat == 0) { src = Wq; dst = Wqt; scale = 0.125f * 1.4426950408889634f; }
  else if (mat == 1) { src = Wk; dst = Wkt; }
  else if (mat == 2) { src = Wv; dst = Wvt; }
  else               { src = Wo; dst = Wot; }
#pragma unroll
  for (int p = 0; p < 4; ++p) {
    int row = p * 16 + (t >> 4), col = (t & 15) * 4;
    const float* a = (mat < 3)
        ? src + ((c0 >> 6) * 512 + i0 + row) * 64 + col
        : src + (i0 + row) * 512 + c0 + col;
    f32x4 v = *(const f32x4*)a;
    T[row * 65 + col + 0] = v[0] * scale;
    T[row * 65 + col + 1] = v[1] * scale;
    T[row * 65 + col + 2] = v[2] * scale;
    T[row * 65 + col + 3] = v[3] * scale;
  }
  __syncthreads();
#pragma unroll
  for (int p = 0; p < 16; ++p) {
    int cc = (t >> 6) * 16 + p, ii = t & 63;
    dst[(c0 + cc) * 512 + i0 + ii] = (f16)T[ii * 65 + cc];
  }
}

// ---------------- K1: fused QKV projection, A read ONCE ----------------
// bid<32: Q-mode, BM=128 rows of q_; 8 waves = 2 row-halves x 4 col-strips.
// bid>=32: KV-mode, BM=64 rows of h; waves 0-3 -> K (512 cols),
//          waves 4-7 -> V (512 cols, transposed store).
// B-frags read directly from global (weights L2-resident), reg double-buffer.
// A-LDS: [chunk(4)][2048B region], addr = chunk*2048+((row*16+chunk*32)&2047)
// -> conflict-free ds_write_b64 staging and ds_read_b128 frag reads.
__global__ __launch_bounds__(512, 2) void proj_kernel(
    const float* __restrict__ q,
    const f16* __restrict__ Wqt, const f16* __restrict__ Wkt, const f16* __restrict__ Wvt,
    f16* __restrict__ Qh, f16* __restrict__ Kh, f16* __restrict__ Vtb)
{
  __shared__ f16 Asl[2][4096];

  int bid = blockIdx.x, tid = threadIdx.x, l = tid & 63, w = tid >> 6;
  bool qmode = bid < 32;

  // staging map: thread -> (row = tid>>3, k-colgroup = tid&7 -> 4 floats)
  int srow = tid >> 3, colg = tid & 7;
  int chunk = colg >> 1, sub = colg & 1;
  const float *ap0, *ap1 = nullptr;
  if (qmode) {
    int m = bid * 128 + srow;
    ap0 = q + ((size_t)((m >> 9) * 4096 + (m & 511))) * 512 + colg * 4;
    int m2 = m + 64;
    ap1 = q + ((size_t)((m2 >> 9) * 4096 + (m2 & 511))) * 512 + colg * 4;
  } else {
    int m = (bid - 32) * 64 + srow;
    int b = m / 3584;
    ap0 = q + ((size_t)(b * 4096 + 512 + (m - b * 3584))) * 512 + colg * 4;
  }
  int wo0 = chunk * 2048 + ((srow * 16 + chunk * 32) & 2047) + sub * 8;
  int wo1 = chunk * 2048 + (((srow + 64) * 16 + chunk * 32) & 2047) + sub * 8;

  // wave roles
  const f16* Wt;
  int wrow;   // wave row base in tile
  if (qmode) { Wt = Wqt; wrow = (w >> 2) * 64; }
  else       { Wt = (w < 4) ? Wkt : Wvt; wrow = 0; }
  int colbase = (w & 3) * 128;
  const f16* bbase = Wt + (size_t)(colbase + (l & 15)) * 512 + (l >> 4) * 8;

  // A-frag read byte offsets
  int ro[4];
#pragma unroll
  for (int mi = 0; mi < 4; ++mi) {
    int row = wrow + mi * 16 + (l & 15);
    ro[mi] = (l >> 4) * 2048 + ((row * 16 + (l >> 4) * 32) & 2047);
  }

  const f32x4 z4 = {0.f, 0.f, 0.f, 0.f};
  f32x4 acc[4][8];
#pragma unroll
  for (int i = 0; i < 4; ++i)
#pragma unroll
    for (int j = 0; j < 8; ++j) acc[i][j] = z4;

  f16x8 bfr[2][8];
  f32x4 ar0, ar1;

  auto awrite = [&](int bufi) {
    f16x4 h4;
    h4[0] = (f16)ar0[0]; h4[1] = (f16)ar0[1]; h4[2] = (f16)ar0[2]; h4[3] = (f16)ar0[3];
    *(f16x4*)((char*)&Asl[bufi][0] + wo0) = h4;
    if (qmode) {
      f16x4 g4;
      g4[0] = (f16)ar1[0]; g4[1] = (f16)ar1[1]; g4[2] = (f16)ar1[2]; g4[3] = (f16)ar1[3];
      *(f16x4*)((char*)&Asl[bufi][0] + wo1) = g4;
    }
  };

  // prologue: k=0
  ar0 = *(const f32x4*)ap0;
  if (qmode) ar1 = *(const f32x4*)ap1;
#pragma unroll
  for (int ni = 0; ni < 8; ++ni)
    bfr[0][ni] = *(const f16x8*)(bbase + ni * 8192);
  awrite(0);
  __syncthreads();

#pragma unroll
  for (int ks = 0; ks < 16; ++ks) {
    int cur = ks & 1;
    f16x8 af[4];
#pragma unroll
    for (int mi = 0; mi < 4; ++mi)
      af[mi] = *(const f16x8*)((const char*)&Asl[cur][0] + ro[mi]);
    if (ks < 15) {
      int k0 = (ks + 1) * 32;
      ar0 = *(const f32x4*)(ap0 + k0);
      if (qmode) ar1 = *(const f32x4*)(ap1 + k0);
#pragma unroll
      for (int ni = 0; ni < 8; ++ni)
        bfr[cur ^ 1][ni] = *(const f16x8*)(bbase + ni * 8192 + k0);
    }
#pragma unroll
    for (int mi = 0; mi < 4; ++mi)
#pragma unroll
      for (int ni = 0; ni < 8; ++ni)
        acc[mi][ni] = MFMA(af[mi], bfr[cur][ni], acc[mi][ni]);
    if (ks < 15) awrite(cur ^ 1);
    __syncthreads();
  }

  // epilogue
  if (qmode) {
    int rowb = bid * 128 + (w >> 2) * 64;
#pragma unroll
    for (int mi = 0; mi < 4; ++mi) {
      int row = rowb + mi * 16 + (l >> 4) * 4;
#pragma unroll
      for (int ni = 0; ni < 8; ++ni) {
        int col = colbase + ni * 16 + (l & 15);
#pragma unroll
        for (int r = 0; r < 4; ++r)
          Qh[(size_t)(row + r) * 512 + col] = (f16)acc[mi][ni][r];
      }
    }
  } else if (w < 4) {
    int rowb = (bid - 32) * 64;
#pragma unroll
    for (int mi = 0; mi < 4; ++mi) {
      int row = rowb + mi * 16 + (l >> 4) * 4;
#pragma unroll
      for (int ni = 0; ni < 8; ++ni) {
        int col = colbase + ni * 16 + (l & 15);
#pragma unroll
        for (int r = 0; r < 4; ++r)
          Kh[(size_t)(row + r) * 512 + col] = (f16)acc[mi][ni][r];
      }
    }
  } else {
    int m0v = (bid - 32) * 64;
    int b = m0v / 3584, g0 = m0v - b * 3584;
#pragma unroll
    for (int mi = 0; mi < 4; ++mi) {
      int g = g0 + mi * 16 + (l >> 4) * 4;
#pragma unroll
      for (int ni = 0; ni < 8; ++ni) {
        int c = colbase + ni * 16 + (l & 15);
        int hh = c >> 6, v = c & 63;
        f16x4 o4;
        o4[0] = (f16)acc[mi][ni][0]; o4[1] = (f16)acc[mi][ni][1];
        o4[2] = (f16)acc[mi][ni][2]; o4[3] = (f16)acc[mi][ni][3];
        *(f16x4*)(Vtb + (size_t)((b * 8 + hh) * 64 + v) * 3584 + g) = o4;
      }
    }
  }
}

// ---------------- K2: flash attention, split-KV x2, swapped-QK^T -------------
__global__ __launch_bounds__(512, 4) void attn_kernel(
    const f16* __restrict__ Qh, const f16* __restrict__ Kh,
    const f16* __restrict__ Vtb, f16* __restrict__ Opart,
    float* __restrict__ Ml, float* __restrict__ Ll)
{
  __shared__ f16 Klds[2][4096];
  __shared__ f16 Vlds[2][4096];
  __shared__ f16 Plds[8 * 1152];

  int bid = blockIdx.x;
  int seg = bid & 1, qt = (bid >> 1) & 3, h = (bid >> 3) & 7, bb = bid >> 6;
  int q0 = qt * 128;
  int tid = threadIdx.x, l = tid & 63, w = tid >> 6;

  f16x8 qf0, qf1;
  {
    int qrow = q0 + w * 16 + (l & 15);
    const f16* qb = Qh + (bb * 512 + qrow) * 512 + h * 64 + ((l >> 4) * 8);
    qf0 = *(const f16x8*)qb;
    qf1 = *(const f16x8*)(qb + 32);
  }

  bool isK = (w < 4);
  int sdo[2], ssrc[2];
#pragma unroll
  for (int j = 0; j < 2; ++j) {
    int id = (isK ? w : (w - 4)) * 2 + j;
    int rr = id * 8 + (l >> 3);
    int co = ((l & 7) ^ (rr & 7)) * 8;
    sdo[j] = id * 512;
    if (isK) ssrc[j] = (bb * 3584 + seg * 1792 + rr) * 512 + h * 64 + co;
    else     ssrc[j] = ((bb * 8 + h) * 64 + rr) * 3584 + seg * 1792 + co;
  }

  const f32x4 z4 = {0.f, 0.f, 0.f, 0.f};
  f32x4 acco[4];
#pragma unroll
  for (int i = 0; i < 4; ++i) acco[i] = z4;
  float mrow = -1e30f, lrow = 0.f;

  char* PwB = (char*)&Plds[w * 1152];
  int pwbase = (l & 15) * 144 + (l >> 4) * 8;
  int prbase = (l & 15) * 144 + (l >> 4) * 16;

  if (isK) { gld16(Kh + ssrc[0], &Klds[0][sdo[0]]); gld16(Kh + ssrc[1], &Klds[0][sdo[1]]); }
  else     { gld16(Vtb + ssrc[0], &Vlds[0][sdo[0]]); gld16(Vtb + ssrc[1], &Vlds[0][sdo[1]]); }
  __syncthreads();

  int buf = 0;
  for (int it = 0; it < 28; ++it) {
    if (it < 27) {
      int g0 = (it + 1) * 64;
      if (isK) { gld16(Kh + ssrc[0] + g0 * 512, &Klds[buf ^ 1][sdo[0]]);
                 gld16(Kh + ssrc[1] + g0 * 512, &Klds[buf ^ 1][sdo[1]]); }
      else     { gld16(Vtb + ssrc[0] + g0, &Vlds[buf ^ 1][sdo[0]]);
                 gld16(Vtb + ssrc[1] + g0, &Vlds[buf ^ 1][sdo[1]]); }
    }
    const char* KB = (const char*)&Klds[buf][0];
    const char* VB = (const char*)&Vlds[buf][0];

    f32x4 accs[4];
#pragma unroll
    for (int i = 0; i < 4; ++i) accs[i] = z4;
#pragma unroll
    for (int ni = 0; ni < 4; ++ni) {
      int g = ni * 16 + (l & 15);
      const char* rp = KB + g * 128;
      f16x8 k0 = *(const f16x8*)(rp + ((((l >> 4)    ) ^ (g & 7)) << 4));
      f16x8 k1 = *(const f16x8*)(rp + (((4 + (l >> 4)) ^ (g & 7)) << 4));
      accs[ni] = MFMA(k0, qf0, accs[ni]);
      accs[ni] = MFMA(k1, qf1, accs[ni]);
    }

    float n0 = fmaxf(fmaxf(accs[0][0], accs[0][1]), fmaxf(accs[0][2], accs[0][3]));
    float n1 = fmaxf(fmaxf(accs[1][0], accs[1][1]), fmaxf(accs[1][2], accs[1][3]));
    float n2 = fmaxf(fmaxf(accs[2][0], accs[2][1]), fmaxf(accs[2][2], accs[2][3]));
    float n3 = fmaxf(fmaxf(accs[3][0], accs[3][1]), fmaxf(accs[3][2], accs[3][3]));
    float tm = fmaxf(fmaxf(n0, n1), fmaxf(n2, n3));
    tm = fmaxf(tm, __shfl_xor(tm, 16));
    tm = fmaxf(tm, __shfl_xor(tm, 32));
    float mn = fmaxf(mrow, tm);
    float alpha = EXP2(mrow - mn);
    mrow = mn;

    float rs = 0.f;
#pragma unroll
    for (int ni = 0; ni < 4; ++ni) {
      float s0 = EXP2(accs[ni][0] - mrow);
      float s1 = EXP2(accs[ni][1] - mrow);
      float s2 = EXP2(accs[ni][2] - mrow);
      float s3 = EXP2(accs[ni][3] - mrow);
      rs += (s0 + s1) + (s2 + s3);
      f16x4 p4;
      p4[0] = (f16)s0; p4[1] = (f16)s1; p4[2] = (f16)s2; p4[3] = (f16)s3;
      *(f16x4*)(PwB + pwbase + ni * 32) = p4;
    }
    rs += __shfl_xor(rs, 16);
    rs += __shfl_xor(rs, 32);
    lrow = lrow * alpha + rs;
#pragma unroll
    for (int ni = 0; ni < 4; ++ni)
#pragma unroll
      for (int r = 0; r < 4; ++r) acco[ni][r] *= alpha;

    asm volatile("s_waitcnt lgkmcnt(0)" ::: "memory");

#pragma unroll
    for (int kc = 0; kc < 2; ++kc) {
      f16x8 pf = *(const f16x8*)(PwB + prbase + kc * 64);
#pragma unroll
      for (int ni = 0; ni < 4; ++ni) {
        int v = ni * 16 + (l & 15);
        f16x8 vf = *(const f16x8*)(VB + v * 128 + (((kc * 4 + (l >> 4)) ^ (v & 7)) << 4));
        acco[ni] = MFMA(vf, pf, acco[ni]);
      }
    }

    __syncthreads();
    buf ^= 1;
  }

  float inv = 1.f / lrow;
  int q = q0 + w * 16 + (l & 15);
  size_t obase = ((size_t)(seg * 64 + bb * 8 + h) * 512 + q) * 64;
#pragma unroll
  for (int ni = 0; ni < 4; ++ni) {
    f16x4 o4;
    o4[0] = (f16)(acco[ni][0] * inv); o4[1] = (f16)(acco[ni][1] * inv);
    o4[2] = (f16)(acco[ni][2] * inv); o4[3] = (f16)(acco[ni][3] * inv);
    *(f16x4*)(Opart + obase + ni * 16 + (l >> 4) * 4) = o4;
  }
  if ((l >> 4) == 0) {
    int mi = (seg * 64 + bb * 8 + h) * 512 + q;
    Ml[mi] = mrow; Ll[mi] = lrow;
  }
}

// ---------------- K2b: merge the two KV segments ----------------
__global__ __launch_bounds__(256) void merge_kernel(
    const f16* __restrict__ Opart, const float* __restrict__ Ml,
    const float* __restrict__ Ll, f16* __restrict__ Hm)
{
  int row = blockIdx.x * 4 + (threadIdx.x >> 6);
  int l = threadIdx.x & 63;
  int bh = row >> 9, q = row & 511;
  int i0 = bh * 512 + q;
  int i1 = (64 + bh) * 512 + q;
  float o0 = (float)Opart[(size_t)i0 * 64 + l];
  float o1 = (float)Opart[(size_t)i1 * 64 + l];
  float m0 = Ml[i0], l0 = Ll[i0], m1 = Ml[i1], l1 = Ll[i1];
  float m = fmaxf(m0, m1);
  float w0 = EXP2(m0 - m) * l0, w1 = EXP2(m1 - m) * l1;
  float o = (w0 * o0 + w1 * o1) / (w0 + w1);
  int bb = bh >> 3, hh = bh & 7;
  Hm[((size_t)(bb * 512 + q)) * 512 + hh * 64 + l] = (f16)o;
}

// ---------------- K3: output projection GEMM ----------------
__global__ __launch_bounds__(256) void outproj_kernel(
    const f16* __restrict__ Hm, const f16* __restrict__ Wot, float* __restrict__ out)
{
  __shared__ f16 Asl[2][4096];
  __shared__ f16 Bsl[2][4096];
  int bid = blockIdx.x;
  int rt = bid >> 2, ct = bid & 3;
  int tid = threadIdx.x, l = tid & 63, w = tid >> 6;
  int m0 = rt * 128, n0 = ct * 128;
  int wr = w >> 1, wc = w & 1;

  int an[2], aco[2];
#pragma unroll
  for (int j = 0; j < 2; ++j) {
    int r = (w * 2 + j) * 16 + (l >> 2);
    an[j] = r;
    aco[j] = ((l & 3) ^ (r & 3)) * 8;
  }

  const f32x4 z4 = {0.f, 0.f, 0.f, 0.f};
  f32x4 acc[4][4];
#pragma unroll
  for (int i = 0; i < 4; ++i)
#pragma unroll
    for (int jj = 0; jj < 4; ++jj) acc[i][jj] = z4;

  auto stage = [&](int bufi, int k0) {
#pragma unroll
    for (int j = 0; j < 2; ++j) {
      gld16(Hm  + (m0 + an[j]) * 512 + k0 + aco[j], &Asl[bufi][(w * 2 + j) * 512]);
      gld16(Wot + (n0 + an[j]) * 512 + k0 + aco[j], &Bsl[bufi][(w * 2 + j) * 512]);
    }
  };

  stage(0, 0);
  __syncthreads();
  for (int ks = 0; ks < 16; ++ks) {
    int bufi = ks & 1;
    if (ks < 15) stage(bufi ^ 1, (ks + 1) * 32);
    const char* AB = (const char*)&Asl[bufi][0];
    const char* BB = (const char*)&Bsl[bufi][0];
    f16x8 af[4], bf[4];
#pragma unroll
    for (int mi = 0; mi < 4; ++mi) {
      int row = wr * 64 + mi * 16 + (l & 15);
      af[mi] = *(const f16x8*)(AB + row * 64 + (((l >> 4) ^ (row & 3)) << 4));
    }
#pragma unroll
    for (int ni = 0; ni < 4; ++ni) {
      int rn = wc * 64 + ni * 16 + (l & 15);
      bf[ni] = *(const f16x8*)(BB + rn * 64 + (((l >> 4) ^ (rn & 3)) << 4));
    }
#pragma unroll
    for (int mi = 0; mi < 4; ++mi)
#pragma unroll
      for (int ni = 0; ni < 4; ++ni)
        acc[mi][ni] = MFMA(af[mi], bf[ni], acc[mi][ni]);
    __syncthreads();
  }

#pragma unroll
  for (int mi = 0; mi < 4; ++mi) {
    int row = m0 + wr * 64 + mi * 16 + (l >> 4) * 4;
#pragma unroll
    for (int ni = 0; ni < 4; ++ni) {
      int col = n0 + wc * 64 + ni * 16 + (l & 15);
#pragma unroll
      for (int r = 0; r < 4; ++r)
        out[(row + r) * 512 + col] = acc[mi][ni][r];
    }
  }
}

extern "C" void kernel_launch(void* const* d_in, const int* in_sizes, int n_in,
                              void* d_out, int out_size, void* d_ws, size_t ws_size,
                              hipStream_t stream) {
  const float* q  = (const float*)d_in[0];
  const float* Wq = (const float*)d_in[1];
  const float* Wk = (const float*)d_in[2];
  const float* Wv = (const float*)d_in[3];
  const float* Wo = (const float*)d_in[4];
  float* out = (float*)d_out;

  f16* ws  = (f16*)d_ws;
  f16* Wqt = ws;                        // 262144
  f16* Wkt = Wqt + 262144;
  f16* Wvt = Wkt + 262144;
  f16* Wot = Wvt + 262144;
  f16* Qh  = Wot + 262144;              // 4096*512
  f16* Kh  = Qh  + 4096 * 512;          // 28672*512
  f16* Vtb = Kh  + 28672 * 512;         // 28672*512 (transposed V)
  f16* Opart = Vtb + 28672 * 512;       // 2*64*512*64
  float* Ml = (float*)(Opart + 2 * 64 * 512 * 64);
  float* Ll = Ml + 65536;
  f16* Hm = Qh;                         // reuse: attn done before merge writes

  transp_w<<<dim3(256),  dim3(256), 0, stream>>>(Wq, Wk, Wv, Wo, Wqt, Wkt, Wvt, Wot);
  proj_kernel<<<dim3(480), dim3(512), 0, stream>>>(q, Wqt, Wkt, Wvt, Qh, Kh, Vtb);
  attn_kernel<<<dim3(512), dim3(512), 0, stream>>>(Qh, Kh, Vtb, Opart, Ml, Ll);
  merge_kernel<<<dim3(8192), dim3(256), 0, stream>>>(Opart, Ml, Ll, Hm);
  outproj_kernel<<<dim3(128), dim3(256), 0, stream>>>(Hm, Wot, out);
}

// Round 4
// 231.609 us; speedup vs baseline: 1.2299x; 1.0472x over previous
//
#include <hip/hip_runtime.h>

typedef _Float16 f16;
typedef _Float16 f16x4 __attribute__((ext_vector_type(4)));
typedef _Float16 f16x8 __attribute__((ext_vector_type(8)));
typedef float    f32x4 __attribute__((ext_vector_type(4)));

#define MFMA(a,b,c) __builtin_amdgcn_mfma_f32_16x16x32_f16(a,b,c,0,0,0)

#if __has_builtin(__builtin_amdgcn_exp2f)
#define EXP2(x) __builtin_amdgcn_exp2f(x)
#else
#define EXP2(x) exp2f(x)
#endif

__device__ __forceinline__ void gld16(const void* g, void* l) {
  typedef __attribute__((address_space(1))) unsigned GU;
  typedef __attribute__((address_space(3))) unsigned LU;
  __builtin_amdgcn_global_load_lds((GU*)g, (LU*)l, 16, 0, 0);
}

// ---------------- K0: weight transpose via LDS tiles ----------------
// mats 0-2: Wt[c][i] = W[h][i][k], c=h*64+k; mat0 scaled by 0.125*log2(e).
// mat 3: Wot[e][hv] = Wo[hv][e].
__global__ __launch_bounds__(256) void transp_w(
    const float* __restrict__ Wq, const float* __restrict__ Wk,
    const float* __restrict__ Wv, const float* __restrict__ Wo,
    f16* __restrict__ Wqt, f16* __restrict__ Wkt, f16* __restrict__ Wvt,
    f16* __restrict__ Wot)
{
  __shared__ float T[64 * 65];
  int bid = blockIdx.x, t = threadIdx.x;
  int mat = bid >> 6;
  int i0 = (bid & 7) * 64, c0 = ((bid >> 3) & 7) * 64;
  const float* src; f16* dst; float scale = 1.f;
  if      (mat == 0) { src = Wq; dst = Wqt; scale = 0.125f * 1.4426950408889634f; }
  else if (mat == 1) { src = Wk; dst = Wkt; }
  else if (mat == 2) { src = Wv; dst = Wvt; }
  else               { src = Wo; dst = Wot; }
#pragma unroll
  for (int p = 0; p < 4; ++p) {
    int row = p * 16 + (t >> 4), col = (t & 15) * 4;
    const float* a = (mat < 3)
        ? src + ((c0 >> 6) * 512 + i0 + row) * 64 + col
        : src + (i0 + row) * 512 + c0 + col;
    f32x4 v = *(const f32x4*)a;
    T[row * 65 + col + 0] = v[0] * scale;
    T[row * 65 + col + 1] = v[1] * scale;
    T[row * 65 + col + 2] = v[2] * scale;
    T[row * 65 + col + 3] = v[3] * scale;
  }
  __syncthreads();
#pragma unroll
  for (int p = 0; p < 16; ++p) {
    int cc = (t >> 6) * 16 + p, ii = t & 63;
    dst[(c0 + cc) * 512 + i0 + ii] = (f16)T[ii * 65 + cc];
  }
}

// ---------------- K1: QKV projection, m97-style 128x128 tiles ----------------
// 1920 tiles: tile<128 -> Q (rt=tile>>2 stripe, ct=tile&3 col-tile of Wq);
// else KV: rt=(tile-128)>>3 stripe (rows 128), cc=(tile-128)&7 col-tile over
// [Wk(4) | Wv(4)]. Chunked XCD swizzle: same-stripe tiles -> same XCD L2.
// Both tiles LDS-staged: B via global_load_lds (inverse-swizzled source),
// A fp32->f16 via registers + swizzled ds_write_b128.
// LDS layout: row r (64B of 32 f16) at r*64, 16B-chunk c stored at
// (c ^ ((r>>1)&3))*16 -> all ds accesses 2-way-per-bank (free).
__global__ __launch_bounds__(256, 3) void proj_kernel(
    const float* __restrict__ q,
    const f16* __restrict__ Wqt, const f16* __restrict__ Wkt, const f16* __restrict__ Wvt,
    f16* __restrict__ Qh, f16* __restrict__ Kh, f16* __restrict__ Vtb)
{
  __shared__ f16 Asl[2][4096];
  __shared__ f16 Bsl[2][4096];

  int bid0 = blockIdx.x;
  int tile = (bid0 & 7) * 240 + (bid0 >> 3);   // XCD-chunked, bijective (1920=8*240)

  int tid = threadIdx.x, l = tid & 63, w = tid >> 6;
  int wr = w >> 1, wc = w & 1;                 // 2x2 wave grid, wave tile 64x64

  bool qmode = tile < 128;
  int rt, colbase, vmode = 0;
  const f16* Wt;
  if (qmode) {
    rt = tile >> 2; colbase = (tile & 3) * 128; Wt = Wqt;
  } else {
    int t2 = tile - 128; rt = t2 >> 3; int cc = t2 & 7;
    if (cc < 4) { Wt = Wkt; colbase = cc * 128; }
    else        { Wt = Wvt; colbase = (cc - 4) * 128; vmode = 1; }
  }
  // uniform global row base for the A stripe (q row index)
  int gbase, bidx;
  if (qmode) { bidx = rt >> 2; gbase = bidx * 4096 + (rt & 3) * 128; }
  else       { bidx = rt / 28; gbase = bidx * 4096 + 512 + (rt * 128 - bidx * 3584); }

  // staging maps: slot s = tid + j*256; row r = s>>2; logical chunk c = (s&3)^((r>>1)&3)
  const float* asrc[2];
  const f16*   bsrc[2];
  int ldst[2];
#pragma unroll
  for (int j = 0; j < 2; ++j) {
    int s = tid + j * 256;
    int r = s >> 2;
    int c = (s & 3) ^ ((r >> 1) & 3);
    asrc[j] = q  + (size_t)(gbase + r) * 512 + c * 8;
    bsrc[j] = Wt + (size_t)(colbase + r) * 512 + c * 8;
    ldst[j] = (j * 256 + w * 64) * 8;          // f16 idx of wave-uniform LDS base
  }
  // A ds_write map: thread covers row r=tid>>1, chunks {2h, 2h+1}, h=tid&1
  int awrow = tid >> 1, awh = tid & 1;
  int awo0 = awrow * 64 + (((awh * 2 + 0) ^ ((awrow >> 1) & 3)) << 4);
  int awo1 = awrow * 64 + (((awh * 2 + 1) ^ ((awrow >> 1) & 3)) << 4);
  const float* awsrc = q + (size_t)(gbase + awrow) * 512 + awh * 16;

  // frag read byte offsets
  int aro[4], bro[4];
#pragma unroll
  for (int i = 0; i < 4; ++i) {
    int ra = wr * 64 + i * 16 + (l & 15);
    aro[i] = ra * 64 + ((((l >> 4)) ^ ((ra >> 1) & 3)) << 4);
    int rb = wc * 64 + i * 16 + (l & 15);
    bro[i] = rb * 64 + ((((l >> 4)) ^ ((rb >> 1) & 3)) << 4);
  }

  const f32x4 z4 = {0.f, 0.f, 0.f, 0.f};
  f32x4 acc[4][4];
#pragma unroll
  for (int i = 0; i < 4; ++i)
#pragma unroll
    for (int j = 0; j < 4; ++j) acc[i][j] = z4;

  f32x4 ar0, ar1, ar2, ar3;   // A fp32 data for the next k-step (2 chunks x 2 halves)

  // prologue: fill buffers for ks=0
  ar0 = *(const f32x4*)(awsrc + 0);
  ar1 = *(const f32x4*)(awsrc + 4);
  ar2 = *(const f32x4*)(awsrc + 8);
  ar3 = *(const f32x4*)(awsrc + 12);
  gld16(bsrc[0], &Bsl[0][ldst[0]]);
  gld16(bsrc[1], &Bsl[0][ldst[1]]);
  {
    f16x8 h0, h1;
#pragma unroll
    for (int e = 0; e < 4; ++e) { h0[e] = (f16)ar0[e]; h0[4+e] = (f16)ar1[e];
                                  h1[e] = (f16)ar2[e]; h1[4+e] = (f16)ar3[e]; }
    *(f16x8*)((char*)&Asl[0][0] + awo0) = h0;
    *(f16x8*)((char*)&Asl[0][0] + awo1) = h1;
  }
  __syncthreads();

  for (int ks = 0; ks < 16; ++ks) {
    int cur = ks & 1;
    if (ks < 15) {
      int k0 = (ks + 1) * 32;
      ar0 = *(const f32x4*)(awsrc + k0 + 0);
      ar1 = *(const f32x4*)(awsrc + k0 + 4);
      ar2 = *(const f32x4*)(awsrc + k0 + 8);
      ar3 = *(const f32x4*)(awsrc + k0 + 12);
      gld16(bsrc[0] + k0, &Bsl[cur ^ 1][ldst[0]]);
      gld16(bsrc[1] + k0, &Bsl[cur ^ 1][ldst[1]]);
    }
    const char* AB = (const char*)&Asl[cur][0];
    const char* BB = (const char*)&Bsl[cur][0];
    f16x8 af[4], bf[4];
#pragma unroll
    for (int i = 0; i < 4; ++i) af[i] = *(const f16x8*)(AB + aro[i]);
#pragma unroll
    for (int i = 0; i < 4; ++i) bf[i] = *(const f16x8*)(BB + bro[i]);
#pragma unroll
    for (int mi = 0; mi < 4; ++mi)
#pragma unroll
      for (int ni = 0; ni < 4; ++ni)
        acc[mi][ni] = MFMA(af[mi], bf[ni], acc[mi][ni]);
    if (ks < 15) {
      f16x8 h0, h1;
#pragma unroll
      for (int e = 0; e < 4; ++e) { h0[e] = (f16)ar0[e]; h0[4+e] = (f16)ar1[e];
                                    h1[e] = (f16)ar2[e]; h1[4+e] = (f16)ar3[e]; }
      *(f16x8*)((char*)&Asl[cur ^ 1][0] + awo0) = h0;
      *(f16x8*)((char*)&Asl[cur ^ 1][0] + awo1) = h1;
    }
    __syncthreads();
  }

  // epilogue
  if (qmode) {
#pragma unroll
    for (int mi = 0; mi < 4; ++mi) {
      int row = rt * 128 + wr * 64 + mi * 16 + (l >> 4) * 4;
#pragma unroll
      for (int ni = 0; ni < 4; ++ni) {
        int col = colbase + wc * 64 + ni * 16 + (l & 15);
#pragma unroll
        for (int r = 0; r < 4; ++r)
          Qh[(size_t)(row + r) * 512 + col] = (f16)acc[mi][ni][r];
      }
    }
  } else if (!vmode) {
#pragma unroll
    for (int mi = 0; mi < 4; ++mi) {
      int row = rt * 128 + wr * 64 + mi * 16 + (l >> 4) * 4;
#pragma unroll
      for (int ni = 0; ni < 4; ++ni) {
        int col = colbase + wc * 64 + ni * 16 + (l & 15);
#pragma unroll
        for (int r = 0; r < 4; ++r)
          Kh[(size_t)(row + r) * 512 + col] = (f16)acc[mi][ni][r];
      }
    }
  } else {
    int g0 = rt * 128 - bidx * 3584;
#pragma unroll
    for (int mi = 0; mi < 4; ++mi) {
      int g = g0 + wr * 64 + mi * 16 + (l >> 4) * 4;
#pragma unroll
      for (int ni = 0; ni < 4; ++ni) {
        int c4 = colbase + wc * 64 + ni * 16 + (l & 15);
        int hh = c4 >> 6, v = c4 & 63;
        f16x4 o4;
        o4[0] = (f16)acc[mi][ni][0]; o4[1] = (f16)acc[mi][ni][1];
        o4[2] = (f16)acc[mi][ni][2]; o4[3] = (f16)acc[mi][ni][3];
        *(f16x4*)(Vtb + (size_t)((bidx * 8 + hh) * 64 + v) * 3584 + g) = o4;
      }
    }
  }
}

// ---------------- K2: flash attention, split-KV x2, swapped-QK^T -------------
__global__ __launch_bounds__(512, 4) void attn_kernel(
    const f16* __restrict__ Qh, const f16* __restrict__ Kh,
    const f16* __restrict__ Vtb, f16* __restrict__ Opart,
    float* __restrict__ Ml, float* __restrict__ Ll)
{
  __shared__ f16 Klds[2][4096];
  __shared__ f16 Vlds[2][4096];
  __shared__ f16 Plds[8 * 1152];

  int bid = blockIdx.x;
  int seg = bid & 1, qt = (bid >> 1) & 3, h = (bid >> 3) & 7, bb = bid >> 6;
  int q0 = qt * 128;
  int tid = threadIdx.x, l = tid & 63, w = tid >> 6;

  f16x8 qf0, qf1;
  {
    int qrow = q0 + w * 16 + (l & 15);
    const f16* qb = Qh + (bb * 512 + qrow) * 512 + h * 64 + ((l >> 4) * 8);
    qf0 = *(const f16x8*)qb;
    qf1 = *(const f16x8*)(qb + 32);
  }

  bool isK = (w < 4);
  int sdo[2], ssrc[2];
#pragma unroll
  for (int j = 0; j < 2; ++j) {
    int id = (isK ? w : (w - 4)) * 2 + j;
    int rr = id * 8 + (l >> 3);
    int co = ((l & 7) ^ (rr & 7)) * 8;
    sdo[j] = id * 512;
    if (isK) ssrc[j] = (bb * 3584 + seg * 1792 + rr) * 512 + h * 64 + co;
    else     ssrc[j] = ((bb * 8 + h) * 64 + rr) * 3584 + seg * 1792 + co;
  }

  const f32x4 z4 = {0.f, 0.f, 0.f, 0.f};
  f32x4 acco[4];
#pragma unroll
  for (int i = 0; i < 4; ++i) acco[i] = z4;
  float mrow = -1e30f, lrow = 0.f;

  char* PwB = (char*)&Plds[w * 1152];
  int pwbase = (l & 15) * 144 + (l >> 4) * 8;
  int prbase = (l & 15) * 144 + (l >> 4) * 16;

  if (isK) { gld16(Kh + ssrc[0], &Klds[0][sdo[0]]); gld16(Kh + ssrc[1], &Klds[0][sdo[1]]); }
  else     { gld16(Vtb + ssrc[0], &Vlds[0][sdo[0]]); gld16(Vtb + ssrc[1], &Vlds[0][sdo[1]]); }
  __syncthreads();

  int buf = 0;
  for (int it = 0; it < 28; ++it) {
    if (it < 27) {
      int g0 = (it + 1) * 64;
      if (isK) { gld16(Kh + ssrc[0] + g0 * 512, &Klds[buf ^ 1][sdo[0]]);
                 gld16(Kh + ssrc[1] + g0 * 512, &Klds[buf ^ 1][sdo[1]]); }
      else     { gld16(Vtb + ssrc[0] + g0, &Vlds[buf ^ 1][sdo[0]]);
                 gld16(Vtb + ssrc[1] + g0, &Vlds[buf ^ 1][sdo[1]]); }
    }
    const char* KB = (const char*)&Klds[buf][0];
    const char* VB = (const char*)&Vlds[buf][0];

    f32x4 accs[4];
#pragma unroll
    for (int i = 0; i < 4; ++i) accs[i] = z4;
#pragma unroll
    for (int ni = 0; ni < 4; ++ni) {
      int g = ni * 16 + (l & 15);
      const char* rp = KB + g * 128;
      f16x8 k0 = *(const f16x8*)(rp + ((((l >> 4)    ) ^ (g & 7)) << 4));
      f16x8 k1 = *(const f16x8*)(rp + (((4 + (l >> 4)) ^ (g & 7)) << 4));
      accs[ni] = MFMA(k0, qf0, accs[ni]);
      accs[ni] = MFMA(k1, qf1, accs[ni]);
    }

    float n0 = fmaxf(fmaxf(accs[0][0], accs[0][1]), fmaxf(accs[0][2], accs[0][3]));
    float n1 = fmaxf(fmaxf(accs[1][0], accs[1][1]), fmaxf(accs[1][2], accs[1][3]));
    float n2 = fmaxf(fmaxf(accs[2][0], accs[2][1]), fmaxf(accs[2][2], accs[2][3]));
    float n3 = fmaxf(fmaxf(accs[3][0], accs[3][1]), fmaxf(accs[3][2], accs[3][3]));
    float tm = fmaxf(fmaxf(n0, n1), fmaxf(n2, n3));
    tm = fmaxf(tm, __shfl_xor(tm, 16));
    tm = fmaxf(tm, __shfl_xor(tm, 32));
    float mn = fmaxf(mrow, tm);
    float alpha = EXP2(mrow - mn);
    mrow = mn;

    float rs = 0.f;
#pragma unroll
    for (int ni = 0; ni < 4; ++ni) {
      float s0 = EXP2(accs[ni][0] - mrow);
      float s1 = EXP2(accs[ni][1] - mrow);
      float s2 = EXP2(accs[ni][2] - mrow);
      float s3 = EXP2(accs[ni][3] - mrow);
      rs += (s0 + s1) + (s2 + s3);
      f16x4 p4;
      p4[0] = (f16)s0; p4[1] = (f16)s1; p4[2] = (f16)s2; p4[3] = (f16)s3;
      *(f16x4*)(PwB + pwbase + ni * 32) = p4;
    }
    rs += __shfl_xor(rs, 16);
    rs += __shfl_xor(rs, 32);
    lrow = lrow * alpha + rs;
#pragma unroll
    for (int ni = 0; ni < 4; ++ni)
#pragma unroll
      for (int r = 0; r < 4; ++r) acco[ni][r] *= alpha;

    asm volatile("s_waitcnt lgkmcnt(0)" ::: "memory");

#pragma unroll
    for (int kc = 0; kc < 2; ++kc) {
      f16x8 pf = *(const f16x8*)(PwB + prbase + kc * 64);
#pragma unroll
      for (int ni = 0; ni < 4; ++ni) {
        int v = ni * 16 + (l & 15);
        f16x8 vf = *(const f16x8*)(VB + v * 128 + (((kc * 4 + (l >> 4)) ^ (v & 7)) << 4));
        acco[ni] = MFMA(vf, pf, acco[ni]);
      }
    }

    __syncthreads();
    buf ^= 1;
  }

  float inv = 1.f / lrow;
  int q = q0 + w * 16 + (l & 15);
  size_t obase = ((size_t)(seg * 64 + bb * 8 + h) * 512 + q) * 64;
#pragma unroll
  for (int ni = 0; ni < 4; ++ni) {
    f16x4 o4;
    o4[0] = (f16)(acco[ni][0] * inv); o4[1] = (f16)(acco[ni][1] * inv);
    o4[2] = (f16)(acco[ni][2] * inv); o4[3] = (f16)(acco[ni][3] * inv);
    *(f16x4*)(Opart + obase + ni * 16 + (l >> 4) * 4) = o4;
  }
  if ((l >> 4) == 0) {
    int mi = (seg * 64 + bb * 8 + h) * 512 + q;
    Ml[mi] = mrow; Ll[mi] = lrow;
  }
}

// ---------------- K2b: merge the two KV segments ----------------
__global__ __launch_bounds__(256) void merge_kernel(
    const f16* __restrict__ Opart, const float* __restrict__ Ml,
    const float* __restrict__ Ll, f16* __restrict__ Hm)
{
  int row = blockIdx.x * 4 + (threadIdx.x >> 6);
  int l = threadIdx.x & 63;
  int bh = row >> 9, q = row & 511;
  int i0 = bh * 512 + q;
  int i1 = (64 + bh) * 512 + q;
  float o0 = (float)Opart[(size_t)i0 * 64 + l];
  float o1 = (float)Opart[(size_t)i1 * 64 + l];
  float m0 = Ml[i0], l0 = Ll[i0], m1 = Ml[i1], l1 = Ll[i1];
  float m = fmaxf(m0, m1);
  float w0 = EXP2(m0 - m) * l0, w1 = EXP2(m1 - m) * l1;
  float o = (w0 * o0 + w1 * o1) / (w0 + w1);
  int bb = bh >> 3, hh = bh & 7;
  Hm[((size_t)(bb * 512 + q)) * 512 + hh * 64 + l] = (f16)o;
}

// ---------------- K3: output projection GEMM ----------------
__global__ __launch_bounds__(256) void outproj_kernel(
    const f16* __restrict__ Hm, const f16* __restrict__ Wot, float* __restrict__ out)
{
  __shared__ f16 Asl[2][4096];
  __shared__ f16 Bsl[2][4096];
  int bid = blockIdx.x;
  int rt = bid >> 2, ct = bid & 3;
  int tid = threadIdx.x, l = tid & 63, w = tid >> 6;
  int m0 = rt * 128, n0 = ct * 128;
  int wr = w >> 1, wc = w & 1;

  int an[2], aco[2];
#pragma unroll
  for (int j = 0; j < 2; ++j) {
    int r = (w * 2 + j) * 16 + (l >> 2);
    an[j] = r;
    aco[j] = ((l & 3) ^ (r & 3)) * 8;
  }

  const f32x4 z4 = {0.f, 0.f, 0.f, 0.f};
  f32x4 acc[4][4];
#pragma unroll
  for (int i = 0; i < 4; ++i)
#pragma unroll
    for (int jj = 0; jj < 4; ++jj) acc[i][jj] = z4;

  auto stage = [&](int bufi, int k0) {
#pragma unroll
    for (int j = 0; j < 2; ++j) {
      gld16(Hm  + (m0 + an[j]) * 512 + k0 + aco[j], &Asl[bufi][(w * 2 + j) * 512]);
      gld16(Wot + (n0 + an[j]) * 512 + k0 + aco[j], &Bsl[bufi][(w * 2 + j) * 512]);
    }
  };

  stage(0, 0);
  __syncthreads();
  for (int ks = 0; ks < 16; ++ks) {
    int bufi = ks & 1;
    if (ks < 15) stage(bufi ^ 1, (ks + 1) * 32);
    const char* AB = (const char*)&Asl[bufi][0];
    const char* BB = (const char*)&Bsl[bufi][0];
    f16x8 af[4], bf[4];
#pragma unroll
    for (int mi = 0; mi < 4; ++mi) {
      int row = wr * 64 + mi * 16 + (l & 15);
      af[mi] = *(const f16x8*)(AB + row * 64 + (((l >> 4) ^ (row & 3)) << 4));
    }
#pragma unroll
    for (int ni = 0; ni < 4; ++ni) {
      int rn = wc * 64 + ni * 16 + (l & 15);
      bf[ni] = *(const f16x8*)(BB + rn * 64 + (((l >> 4) ^ (rn & 3)) << 4));
    }
#pragma unroll
    for (int mi = 0; mi < 4; ++mi)
#pragma unroll
      for (int ni = 0; ni < 4; ++ni)
        acc[mi][ni] = MFMA(af[mi], bf[ni], acc[mi][ni]);
    __syncthreads();
  }

#pragma unroll
  for (int mi = 0; mi < 4; ++mi) {
    int row = m0 + wr * 64 + mi * 16 + (l >> 4) * 4;
#pragma unroll
    for (int ni = 0; ni < 4; ++ni) {
      int col = n0 + wc * 64 + ni * 16 + (l & 15);
#pragma unroll
      for (int r = 0; r < 4; ++r)
        out[(row + r) * 512 + col] = acc[mi][ni][r];
    }
  }
}

extern "C" void kernel_launch(void* const* d_in, const int* in_sizes, int n_in,
                              void* d_out, int out_size, void* d_ws, size_t ws_size,
                              hipStream_t stream) {
  const float* q  = (const float*)d_in[0];
  const float* Wq = (const float*)d_in[1];
  const float* Wk = (const float*)d_in[2];
  const float* Wv = (const float*)d_in[3];
  const float* Wo = (const float*)d_in[4];
  float* out = (float*)d_out;

  f16* ws  = (f16*)d_ws;
  f16* Wqt = ws;                        // 262144
  f16* Wkt = Wqt + 262144;
  f16* Wvt = Wkt + 262144;
  f16* Wot = Wvt + 262144;
  f16* Qh  = Wot + 262144;              // 4096*512
  f16* Kh  = Qh  + 4096 * 512;          // 28672*512
  f16* Vtb = Kh  + 28672 * 512;         // 28672*512 (transposed V)
  f16* Opart = Vtb + 28672 * 512;       // 2*64*512*64
  float* Ml = (float*)(Opart + 2 * 64 * 512 * 64);
  float* Ll = Ml + 65536;
  f16* Hm = Qh;                         // reuse: attn done before merge writes

  transp_w<<<dim3(256),  dim3(256), 0, stream>>>(Wq, Wk, Wv, Wo, Wqt, Wkt, Wvt, Wot);
  proj_kernel<<<dim3(1920), dim3(256), 0, stream>>>(q, Wqt, Wkt, Wvt, Qh, Kh, Vtb);
  attn_kernel<<<dim3(512), dim3(512), 0, stream>>>(Qh, Kh, Vtb, Opart, Ml, Ll);
  merge_kernel<<<dim3(8192), dim3(256), 0, stream>>>(Opart, Ml, Ll, Hm);
  outproj_kernel<<<dim3(128), dim3(256), 0, stream>>>(Hm, Wot, out);
}